// Round 1
// baseline (4967.958 us; speedup 1.0000x reference)
//
#include <hip/hip_runtime.h>
#include <math.h>

#define NNODES 40000
#define CCH    128
#define NH     8
#define HD     16
#define NEDGE  640000
#define SGRID  2048

// ---------------- LayerNorm: 4 waves/block, 1 row/wave ----------------
__global__ __launch_bounds__(256) void k_ln(const float* __restrict__ x,
                                            const float* __restrict__ g,
                                            const float* __restrict__ b,
                                            float* __restrict__ out) {
  int wave = threadIdx.x >> 6;
  int lane = threadIdx.x & 63;
  int row  = blockIdx.x * 4 + wave;
  if (row >= NNODES) return;
  const float2* xr = (const float2*)(x + (size_t)row * CCH);
  float2 v = xr[lane];
  float s  = v.x + v.y;
  float ss = v.x * v.x + v.y * v.y;
  #pragma unroll
  for (int d = 1; d < 64; d <<= 1) {
    s  += __shfl_xor(s, d);
    ss += __shfl_xor(ss, d);
  }
  float mean = s * (1.0f / CCH);
  float var  = ss * (1.0f / CCH) - mean * mean;
  float rstd = rsqrtf(var + 1e-5f);
  float2 gg = ((const float2*)g)[lane];
  float2 bb = ((const float2*)b)[lane];
  float2 o;
  o.x = (v.x - mean) * rstd * gg.x + bb.x;
  o.y = (v.y - mean) * rstd * gg.y + bb.y;
  ((float2*)(out + (size_t)row * CCH))[lane] = o;
}

// ---------------- Generic fp32 GEMM: out = [res +] A@W + bias [, relu] ----
// A: [M,K], W: [K,Nc] row-major. Block: 256 thr -> 64 rows x 128 cols tile.
template <bool RELU, bool RES>
__global__ __launch_bounds__(256) void k_gemm(const float* __restrict__ A,
                                              const float* __restrict__ W,
                                              const float* __restrict__ bias,
                                              const float* __restrict__ res,
                                              float* __restrict__ out,
                                              int K, int Nc) {
  const int KC = 64;
  __shared__ float xs[64][68];    // [row][k], pad 68
  __shared__ float ws[64][132];   // [k][col], pad 132
  const int row0 = blockIdx.x * 64;
  const int c0   = blockIdx.y * 128;
  const int tid  = threadIdx.x;
  const int tc   = tid & 31;   // col group (4 consecutive cols)
  const int tr   = tid >> 5;   // 0..7 row phase

  float4 acc[8];
  #pragma unroll
  for (int i = 0; i < 8; i++) acc[i] = make_float4(0.f, 0.f, 0.f, 0.f);

  for (int kc = 0; kc < K; kc += KC) {
    __syncthreads();
    // stage A tile: 64 rows x 64 k
    {
      int k4 = (tid & 15) * 4;
      int r  = tid >> 4;           // 0..15
      #pragma unroll
      for (int it = 0; it < 4; it++) {
        float4 vv = *(const float4*)(A + (size_t)(row0 + r + 16 * it) * K + kc + k4);
        *(float4*)&xs[r + 16 * it][k4] = vv;
      }
    }
    // stage W tile: 64 k x 128 cols (natural layout)
    {
      int c4 = (tid & 31) * 4;
      int kk = tid >> 5;           // 0..7
      #pragma unroll
      for (int it = 0; it < 8; it++) {
        float4 vv = *(const float4*)(W + (size_t)(kc + kk + 8 * it) * Nc + c0 + c4);
        *(float4*)&ws[kk + 8 * it][c4] = vv;
      }
    }
    __syncthreads();
    #pragma unroll 4
    for (int k = 0; k < KC; k++) {
      float4 wv = *(const float4*)&ws[k][tc * 4];
      #pragma unroll
      for (int i = 0; i < 8; i++) {
        float xv = xs[tr + 8 * i][k];
        acc[i].x += xv * wv.x;
        acc[i].y += xv * wv.y;
        acc[i].z += xv * wv.z;
        acc[i].w += xv * wv.w;
      }
    }
  }

  float4 bv = *(const float4*)(bias + c0 + tc * 4);
  #pragma unroll
  for (int i = 0; i < 8; i++) {
    size_t r = (size_t)(row0 + tr + 8 * i);
    float4 o = acc[i];
    o.x += bv.x; o.y += bv.y; o.z += bv.z; o.w += bv.w;
    if (RES) {
      float4 rv = *(const float4*)(res + r * Nc + c0 + tc * 4);
      o.x += rv.x; o.y += rv.y; o.z += rv.z; o.w += rv.w;
    }
    if (RELU) {
      o.x = fmaxf(o.x, 0.f); o.y = fmaxf(o.y, 0.f);
      o.z = fmaxf(o.z, 0.f); o.w = fmaxf(o.w, 0.f);
    }
    *(float4*)(out + r * Nc + c0 + tc * 4) = o;
  }
}

// ---------------- Edge scores + exp + per-head partial sums ----------------
__global__ __launch_bounds__(256) void k_scores(const float* __restrict__ q,
                                                const float* __restrict__ k,
                                                const int* __restrict__ ei,
                                                float* __restrict__ wscore,
                                                float* __restrict__ hpartial) {
  const int tid  = threadIdx.x;
  const int gid0 = blockIdx.x * 256 + tid;
  const int total = NEDGE * NH;
  float lsum = 0.f;
  for (int gid = gid0; gid < total; gid += SGRID * 256) {
    int e = gid >> 3;
    int h = gid & 7;
    int src = ei[e];
    int dst = ei[NEDGE + e];
    const float4* qr = (const float4*)(q + (size_t)dst * CCH + h * HD);
    const float4* kr = (const float4*)(k + (size_t)src * CCH + h * HD);
    float s = 0.f;
    #pragma unroll
    for (int i = 0; i < 4; i++) {
      float4 a = qr[i], bb = kr[i];
      s += a.x * bb.x + a.y * bb.y + a.z * bb.z + a.w * bb.w;
    }
    float es = __expf(s * 0.25f);
    wscore[gid] = es;
    lsum += es;
  }
  // reduce across lanes sharing h = tid&7
  #pragma unroll
  for (int d = 8; d < 64; d <<= 1) lsum += __shfl_xor(lsum, d);
  __shared__ float wsum[4][8];
  int lane = tid & 63, wv = tid >> 6;
  if (lane < 8) wsum[wv][lane] = lsum;
  __syncthreads();
  if (tid < 8) {
    hpartial[blockIdx.x * 8 + tid] =
        wsum[0][tid] + wsum[1][tid] + wsum[2][tid] + wsum[3][tid];
  }
}

__global__ __launch_bounds__(256) void k_reduce_inv(const float* __restrict__ hpartial,
                                                    float* __restrict__ inv) {
  const int tid = threadIdx.x;
  const int h = tid & 7;
  float s = 0.f;
  for (int i = tid >> 3; i < SGRID; i += 32) s += hpartial[i * 8 + h];
  #pragma unroll
  for (int d = 8; d < 64; d <<= 1) s += __shfl_xor(s, d);
  __shared__ float wsum[4][8];
  int lane = tid & 63, wv = tid >> 6;
  if (lane < 8) wsum[wv][lane] = s;
  __syncthreads();
  if (tid < 8) {
    float t = wsum[0][tid] + wsum[1][tid] + wsum[2][tid] + wsum[3][tid];
    inv[tid] = 1.0f / t;
  }
}

// ---------------- Weighted scatter-add into aggregated ----------------
__global__ __launch_bounds__(256) void k_aggregate(const float* __restrict__ v,
                                                   const float* __restrict__ wscore,
                                                   const float* __restrict__ inv,
                                                   const int* __restrict__ ei,
                                                   float* __restrict__ agg) {
  int gid = blockIdx.x * 256 + threadIdx.x;
  if (gid >= NEDGE * NH) return;
  int e = gid >> 3;
  int h = gid & 7;
  int src = ei[e];
  int dst = ei[NEDGE + e];
  float w = wscore[gid] * inv[h];
  const float4* vr = (const float4*)(v + (size_t)src * CCH + h * HD);
  float* ar = agg + (size_t)dst * CCH + h * HD;
  #pragma unroll
  for (int i = 0; i < 4; i++) {
    float4 vv = vr[i];
    __hip_atomic_fetch_add(ar + i * 4 + 0, vv.x * w, __ATOMIC_RELAXED, __HIP_MEMORY_SCOPE_AGENT);
    __hip_atomic_fetch_add(ar + i * 4 + 1, vv.y * w, __ATOMIC_RELAXED, __HIP_MEMORY_SCOPE_AGENT);
    __hip_atomic_fetch_add(ar + i * 4 + 2, vv.z * w, __ATOMIC_RELAXED, __HIP_MEMORY_SCOPE_AGENT);
    __hip_atomic_fetch_add(ar + i * 4 + 3, vv.w * w, __ATOMIC_RELAXED, __HIP_MEMORY_SCOPE_AGENT);
  }
}

extern "C" void kernel_launch(void* const* d_in, const int* in_sizes, int n_in,
                              void* d_out, int out_size, void* d_ws, size_t ws_size,
                              hipStream_t stream) {
  const float* x    = (const float*)d_in[0];
  const int*   ei   = (const int*)d_in[1];
  const float* Wq   = (const float*)d_in[2];
  const float* bq   = (const float*)d_in[3];
  const float* Wk   = (const float*)d_in[4];
  const float* bk   = (const float*)d_in[5];
  const float* Wv   = (const float*)d_in[6];
  const float* bv   = (const float*)d_in[7];
  const float* Wo   = (const float*)d_in[8];
  const float* bo   = (const float*)d_in[9];
  const float* ln1g = (const float*)d_in[10];
  const float* ln1b = (const float*)d_in[11];
  const float* ln2g = (const float*)d_in[12];
  const float* ln2b = (const float*)d_in[13];
  const float* W1   = (const float*)d_in[14];
  const float* b1   = (const float*)d_in[15];
  const float* W2   = (const float*)d_in[16];
  const float* b2   = (const float*)d_in[17];
  float* out = (float*)d_out;

  float* ws = (float*)d_ws;
  const size_t NC = (size_t)NNODES * CCH;  // 5.12M floats
  float* xn     = ws;              // later reused as xn2
  float* q      = ws + 1 * NC;     // later reused as agg
  float* kk     = ws + 2 * NC;     // later reused as x1
  float* vv     = ws + 3 * NC;     // ffn1 overlays 3NC..7NC after edge phase
  float* wscore = ws + 4 * NC;
  float* ffn1   = ws + 3 * NC;
  float* hpart  = ws + 7 * NC;
  float* inv    = hpart + SGRID * 8;
  float* agg = q;
  float* x1  = kk;
  float* xn2 = xn;

  dim3 blk(256);
  dim3 gLN(NNODES / 4);
  dim3 g128(NNODES / 64, 1);
  dim3 g512(NNODES / 64, 4);

  // LN1
  k_ln<<<gLN, blk, 0, stream>>>(x, ln1g, ln1b, xn);
  // QKV
  k_gemm<false, false><<<g128, blk, 0, stream>>>(xn, Wq, bq, nullptr, q, CCH, CCH);
  k_gemm<false, false><<<g128, blk, 0, stream>>>(xn, Wk, bk, nullptr, kk, CCH, CCH);
  k_gemm<false, false><<<g128, blk, 0, stream>>>(xn, Wv, bv, nullptr, vv, CCH, CCH);
  // edge scores -> exp + per-head partial sums
  k_scores<<<SGRID, blk, 0, stream>>>(q, kk, ei, wscore, hpart);
  k_reduce_inv<<<1, blk, 0, stream>>>(hpart, inv);
  // weighted scatter-add (agg overlays q, dead now)
  hipMemsetAsync(agg, 0, NC * sizeof(float), stream);
  k_aggregate<<<(NEDGE * NH + 255) / 256, blk, 0, stream>>>(vv, wscore, inv, ei, agg);
  // out-proj + residual -> x1 (overlays k, dead now)
  k_gemm<false, true><<<g128, blk, 0, stream>>>(agg, Wo, bo, x, x1, CCH, CCH);
  // LN2 (xn2 overlays xn)
  k_ln<<<gLN, blk, 0, stream>>>(x1, ln2g, ln2b, xn2);
  // FFN
  k_gemm<true, false><<<g512, blk, 0, stream>>>(xn2, W1, b1, nullptr, ffn1, CCH, 4 * CCH);
  k_gemm<false, true><<<g128, blk, 0, stream>>>(ffn1, W2, b2, x1, out, 4 * CCH, CCH);
}

// Round 2
// 589.400 us; speedup vs baseline: 8.4288x; 8.4288x over previous
//
#include <hip/hip_runtime.h>
#include <math.h>

#define NNODES 40000
#define CCH    128
#define NH     8
#define HD     16
#define NEDGE  640000
#define SGRID  2048

// ---------------- LayerNorm: 4 waves/block, 1 row/wave ----------------
__global__ __launch_bounds__(256) void k_ln(const float* __restrict__ x,
                                            const float* __restrict__ g,
                                            const float* __restrict__ b,
                                            float* __restrict__ out) {
  int wave = threadIdx.x >> 6;
  int lane = threadIdx.x & 63;
  int row  = blockIdx.x * 4 + wave;
  if (row >= NNODES) return;
  const float2* xr = (const float2*)(x + (size_t)row * CCH);
  float2 v = xr[lane];
  float s  = v.x + v.y;
  float ss = v.x * v.x + v.y * v.y;
  #pragma unroll
  for (int d = 1; d < 64; d <<= 1) {
    s  += __shfl_xor(s, d);
    ss += __shfl_xor(ss, d);
  }
  float mean = s * (1.0f / CCH);
  float var  = ss * (1.0f / CCH) - mean * mean;
  float rstd = rsqrtf(var + 1e-5f);
  float2 gg = ((const float2*)g)[lane];
  float2 bb = ((const float2*)b)[lane];
  float2 o;
  o.x = (v.x - mean) * rstd * gg.x + bb.x;
  o.y = (v.y - mean) * rstd * gg.y + bb.y;
  ((float2*)(out + (size_t)row * CCH))[lane] = o;
}

// ---------------- Generic fp32 GEMM: out = [res +] A@W + bias [, relu] ----
template <bool RELU, bool RES>
__global__ __launch_bounds__(256) void k_gemm(const float* __restrict__ A,
                                              const float* __restrict__ W,
                                              const float* __restrict__ bias,
                                              const float* __restrict__ res,
                                              float* __restrict__ out,
                                              int K, int Nc) {
  const int KC = 64;
  __shared__ float xs[64][68];
  __shared__ float ws[64][132];
  const int row0 = blockIdx.x * 64;
  const int c0   = blockIdx.y * 128;
  const int tid  = threadIdx.x;
  const int tc   = tid & 31;
  const int tr   = tid >> 5;

  float4 acc[8];
  #pragma unroll
  for (int i = 0; i < 8; i++) acc[i] = make_float4(0.f, 0.f, 0.f, 0.f);

  for (int kc = 0; kc < K; kc += KC) {
    __syncthreads();
    {
      int k4 = (tid & 15) * 4;
      int r  = tid >> 4;
      #pragma unroll
      for (int it = 0; it < 4; it++) {
        float4 vv = *(const float4*)(A + (size_t)(row0 + r + 16 * it) * K + kc + k4);
        *(float4*)&xs[r + 16 * it][k4] = vv;
      }
    }
    {
      int c4 = (tid & 31) * 4;
      int kk = tid >> 5;
      #pragma unroll
      for (int it = 0; it < 8; it++) {
        float4 vv = *(const float4*)(W + (size_t)(kc + kk + 8 * it) * Nc + c0 + c4);
        *(float4*)&ws[kk + 8 * it][c4] = vv;
      }
    }
    __syncthreads();
    #pragma unroll 4
    for (int k = 0; k < KC; k++) {
      float4 wv = *(const float4*)&ws[k][tc * 4];
      #pragma unroll
      for (int i = 0; i < 8; i++) {
        float xv = xs[tr + 8 * i][k];
        acc[i].x += xv * wv.x;
        acc[i].y += xv * wv.y;
        acc[i].z += xv * wv.z;
        acc[i].w += xv * wv.w;
      }
    }
  }

  float4 bv = *(const float4*)(bias + c0 + tc * 4);
  #pragma unroll
  for (int i = 0; i < 8; i++) {
    size_t r = (size_t)(row0 + tr + 8 * i);
    float4 o = acc[i];
    o.x += bv.x; o.y += bv.y; o.z += bv.z; o.w += bv.w;
    if (RES) {
      float4 rv = *(const float4*)(res + r * Nc + c0 + tc * 4);
      o.x += rv.x; o.y += rv.y; o.z += rv.z; o.w += rv.w;
    }
    if (RELU) {
      o.x = fmaxf(o.x, 0.f); o.y = fmaxf(o.y, 0.f);
      o.z = fmaxf(o.z, 0.f); o.w = fmaxf(o.w, 0.f);
    }
    *(float4*)(out + r * Nc + c0 + tc * 4) = o;
  }
}

// ---------------- Edge scores + exp + per-head partial sums ----------------
__global__ __launch_bounds__(256) void k_scores(const float* __restrict__ q,
                                                const float* __restrict__ k,
                                                const int* __restrict__ ei,
                                                float* __restrict__ wscore,
                                                float* __restrict__ hpartial) {
  const int tid  = threadIdx.x;
  const int gid0 = blockIdx.x * 256 + tid;
  const int total = NEDGE * NH;
  float lsum = 0.f;
  for (int gid = gid0; gid < total; gid += SGRID * 256) {
    int e = gid >> 3;
    int h = gid & 7;
    int src = ei[e];
    int dst = ei[NEDGE + e];
    const float4* qr = (const float4*)(q + (size_t)dst * CCH + h * HD);
    const float4* kr = (const float4*)(k + (size_t)src * CCH + h * HD);
    float s = 0.f;
    #pragma unroll
    for (int i = 0; i < 4; i++) {
      float4 a = qr[i], bb = kr[i];
      s += a.x * bb.x + a.y * bb.y + a.z * bb.z + a.w * bb.w;
    }
    float es = __expf(s * 0.25f);
    wscore[gid] = es;
    lsum += es;
  }
  #pragma unroll
  for (int d = 8; d < 64; d <<= 1) lsum += __shfl_xor(lsum, d);
  __shared__ float wsum[4][8];
  int lane = tid & 63, wv = tid >> 6;
  if (lane < 8) wsum[wv][lane] = lsum;
  __syncthreads();
  if (tid < 8) {
    hpartial[blockIdx.x * 8 + tid] =
        wsum[0][tid] + wsum[1][tid] + wsum[2][tid] + wsum[3][tid];
  }
}

__global__ __launch_bounds__(256) void k_reduce_inv(const float* __restrict__ hpartial,
                                                    float* __restrict__ inv) {
  const int tid = threadIdx.x;
  const int h = tid & 7;
  float s = 0.f;
  for (int i = tid >> 3; i < SGRID; i += 32) s += hpartial[i * 8 + h];
  #pragma unroll
  for (int d = 8; d < 64; d <<= 1) s += __shfl_xor(s, d);
  __shared__ float wsum[4][8];
  int lane = tid & 63, wv = tid >> 6;
  if (lane < 8) wsum[wv][lane] = s;
  __syncthreads();
  if (tid < 8) {
    float t = wsum[0][tid] + wsum[1][tid] + wsum[2][tid] + wsum[3][tid];
    inv[tid] = 1.0f / t;
  }
}

// ---------------- CSR build: histogram -> scan -> scatter ----------------
__global__ __launch_bounds__(256) void k_hist(const int* __restrict__ ei,
                                              int* __restrict__ deg) {
  int e = blockIdx.x * 256 + threadIdx.x;
  if (e >= NEDGE) return;
  atomicAdd(&deg[ei[NEDGE + e]], 1);
}

__global__ __launch_bounds__(256) void k_scan(const int* __restrict__ deg,
                                              int* __restrict__ off,
                                              int* __restrict__ cursor) {
  const int T = 157;  // ceil(40000/256)
  int t = threadIdx.x;
  int start = t * T;
  int end   = start + T; if (end > NNODES) end = NNODES;
  int s = 0;
  for (int i = start; i < end && i < NNODES; i++) s += deg[i];
  int lane = t & 63, wv = t >> 6;
  int vincl = s;
  #pragma unroll
  for (int d = 1; d < 64; d <<= 1) {
    int o = __shfl_up(vincl, d);
    if (lane >= d) vincl += o;
  }
  __shared__ int wsum[4];
  if (lane == 63) wsum[wv] = vincl;
  __syncthreads();
  int base = 0;
  for (int w = 0; w < wv; w++) base += wsum[w];
  int run = base + vincl - s;  // exclusive prefix for this thread's chunk
  for (int i = start; i < end && i < NNODES; i++) {
    off[i] = run; cursor[i] = run;
    run += deg[i];
  }
  if (t == 255) off[NNODES] = run;
}

__global__ __launch_bounds__(256) void k_scatter(const int* __restrict__ ei,
                                                 int* __restrict__ cursor,
                                                 int* __restrict__ sorted) {
  int e = blockIdx.x * 256 + threadIdx.x;
  if (e >= NEDGE) return;
  int pos = atomicAdd(&cursor[ei[NEDGE + e]], 1);
  sorted[pos] = e;
}

// ---------------- Gather aggregation: 1 wave per dst node ----------------
__global__ __launch_bounds__(256) void k_agg2(const float* __restrict__ v,
                                              const float* __restrict__ wscore,
                                              const float* __restrict__ inv,
                                              const int* __restrict__ ei,
                                              const int* __restrict__ off,
                                              const int* __restrict__ sorted,
                                              float* __restrict__ agg) {
  int wave = threadIdx.x >> 6;
  int lane = threadIdx.x & 63;
  int n = blockIdx.x * 4 + wave;
  if (n >= NNODES) return;
  int c = lane * 2;        // this lane's channel pair
  int h = lane >> 3;       // head for these channels
  float winv = inv[h];
  float2 acc = make_float2(0.f, 0.f);
  int i0 = off[n], i1 = off[n + 1];
  for (int i = i0; i < i1; i += 64) {
    int cnt = i1 - i; if (cnt > 64) cnt = 64;
    int e_l = (i + lane < i1) ? sorted[i + lane] : 0;
    int s_l = (i + lane < i1) ? ei[e_l] : 0;
    for (int j = 0; j < cnt; j++) {
      int e   = __shfl(e_l, j);
      int src = __shfl(s_l, j);
      float w = wscore[(size_t)e * NH + h] * winv;
      float2 vv = *(const float2*)(v + (size_t)src * CCH + c);
      acc.x += w * vv.x;
      acc.y += w * vv.y;
    }
  }
  *(float2*)(agg + (size_t)n * CCH + c) = acc;
}

extern "C" void kernel_launch(void* const* d_in, const int* in_sizes, int n_in,
                              void* d_out, int out_size, void* d_ws, size_t ws_size,
                              hipStream_t stream) {
  const float* x    = (const float*)d_in[0];
  const int*   ei   = (const int*)d_in[1];
  const float* Wq   = (const float*)d_in[2];
  const float* bq   = (const float*)d_in[3];
  const float* Wk   = (const float*)d_in[4];
  const float* bk   = (const float*)d_in[5];
  const float* Wv   = (const float*)d_in[6];
  const float* bv   = (const float*)d_in[7];
  const float* Wo   = (const float*)d_in[8];
  const float* bo   = (const float*)d_in[9];
  const float* ln1g = (const float*)d_in[10];
  const float* ln1b = (const float*)d_in[11];
  const float* ln2g = (const float*)d_in[12];
  const float* ln2b = (const float*)d_in[13];
  const float* W1   = (const float*)d_in[14];
  const float* b1   = (const float*)d_in[15];
  const float* W2   = (const float*)d_in[16];
  const float* b2   = (const float*)d_in[17];
  float* out = (float*)d_out;

  float* ws = (float*)d_ws;
  const size_t NC = (size_t)NNODES * CCH;  // 5.12M floats
  float* xn     = ws;              // buf0; later xn2
  float* q      = ws + 1 * NC;     // buf1; later agg
  float* kk     = ws + 2 * NC;     // buf2; later x1
  float* vv     = ws + 3 * NC;     // buf3; ffn1 = buf3..buf6
  float* wscore = ws + 4 * NC;     // buf4
  // buf5: CSR scratch (dead once ffn1 is computed)
  int*   deg    = (int*)(ws + 5 * NC);
  int*   off    = deg + NNODES;            // NNODES+1
  int*   cursor = deg + 2 * NNODES + 64;
  int*   sorted = deg + 3 * NNODES + 128;
  float* ffn1   = ws + 3 * NC;
  float* hpart  = ws + 7 * NC;
  float* inv    = hpart + SGRID * 8;
  float* agg = q;
  float* x1  = kk;
  float* xn2 = xn;

  dim3 blk(256);
  dim3 gLN(NNODES / 4);
  dim3 g128(NNODES / 64, 1);
  dim3 g512(NNODES / 64, 4);
  dim3 gE((NEDGE + 255) / 256);

  // CSR build (depends only on ei)
  hipMemsetAsync(deg, 0, NNODES * sizeof(int), stream);
  k_hist<<<gE, blk, 0, stream>>>(ei, deg);
  k_scan<<<1, blk, 0, stream>>>(deg, off, cursor);
  k_scatter<<<gE, blk, 0, stream>>>(ei, cursor, sorted);

  // LN1 + QKV
  k_ln<<<gLN, blk, 0, stream>>>(x, ln1g, ln1b, xn);
  k_gemm<false, false><<<g128, blk, 0, stream>>>(xn, Wq, bq, nullptr, q, CCH, CCH);
  k_gemm<false, false><<<g128, blk, 0, stream>>>(xn, Wk, bk, nullptr, kk, CCH, CCH);
  k_gemm<false, false><<<g128, blk, 0, stream>>>(xn, Wv, bv, nullptr, vv, CCH, CCH);

  // edge scores -> exp + global-softmax denominator
  k_scores<<<SGRID, blk, 0, stream>>>(q, kk, ei, wscore, hpart);
  k_reduce_inv<<<1, blk, 0, stream>>>(hpart, inv);

  // gather aggregation (agg overlays q, dead now)
  k_agg2<<<gLN, blk, 0, stream>>>(vv, wscore, inv, ei, off, sorted, agg);

  // out-proj + residual -> x1 (overlays kk)
  k_gemm<false, true><<<g128, blk, 0, stream>>>(agg, Wo, bo, x, x1, CCH, CCH);
  // LN2
  k_ln<<<gLN, blk, 0, stream>>>(x1, ln2g, ln2b, xn2);
  // FFN
  k_gemm<true, false><<<g512, blk, 0, stream>>>(xn2, W1, b1, nullptr, ffn1, CCH, 4 * CCH);
  k_gemm<false, true><<<g128, blk, 0, stream>>>(ffn1, W2, b2, x1, out, 4 * CCH, CCH);
}

// Round 3
// 282.228 us; speedup vs baseline: 17.6027x; 2.0884x over previous
//
#include <hip/hip_runtime.h>
#include <math.h>

#define NNODES 40000
#define CCH    128
#define NH     8
#define HD     16
#define NEDGE  640000
#define SGRID  2048
#define NBLK   157   // ceil(NNODES/256)

typedef __attribute__((ext_vector_type(8))) short bf16x8;
typedef __attribute__((ext_vector_type(4))) float f32x4;

__device__ inline unsigned short f2bf(float f) {
  union { float f; unsigned u; } c; c.f = f;
  unsigned r = c.u + 0x7fffu + ((c.u >> 16) & 1u);
  return (unsigned short)(r >> 16);
}
__device__ inline float bflo(unsigned u) { union { unsigned i; float f; } c; c.i = u << 16; return c.f; }
__device__ inline float bfhi(unsigned u) { union { unsigned i; float f; } c; c.i = u & 0xffff0000u; return c.f; }

// ---------------- LayerNorm: 4 waves/block, 1 row/wave, bf16 out ----------
__global__ __launch_bounds__(256) void k_ln_bf(const float* __restrict__ x,
                                               const float* __restrict__ g,
                                               const float* __restrict__ b,
                                               unsigned* __restrict__ out) {
  int wave = threadIdx.x >> 6;
  int lane = threadIdx.x & 63;
  int row  = blockIdx.x * 4 + wave;
  if (row >= NNODES) return;
  const float2* xr = (const float2*)(x + (size_t)row * CCH);
  float2 v = xr[lane];
  float s  = v.x + v.y;
  float ss = v.x * v.x + v.y * v.y;
  #pragma unroll
  for (int d = 1; d < 64; d <<= 1) {
    s  += __shfl_xor(s, d);
    ss += __shfl_xor(ss, d);
  }
  float mean = s * (1.0f / CCH);
  float var  = ss * (1.0f / CCH) - mean * mean;
  float rstd = rsqrtf(var + 1e-5f);
  float2 gg = ((const float2*)g)[lane];
  float2 bb = ((const float2*)b)[lane];
  float ox = (v.x - mean) * rstd * gg.x + bb.x;
  float oy = (v.y - mean) * rstd * gg.y + bb.y;
  out[(size_t)row * 64 + lane] = ((unsigned)f2bf(oy) << 16) | f2bf(ox);
}

// ---------------- Weight prep: transpose + bf16 convert -------------------
// W [K][Nc] fp32 -> Wt [Nc][K] bf16
__global__ __launch_bounds__(256) void k_wprep(const float* __restrict__ W,
                                               unsigned short* __restrict__ Wt,
                                               int K, int Nc) {
  int idx = blockIdx.x * 256 + threadIdx.x;
  if (idx >= K * Nc) return;
  int n = idx / K, k = idx - n * K;
  Wt[idx] = f2bf(W[(size_t)k * Nc + n]);
}

// ---------------- MFMA GEMM: out = [res +] A@W + bias [,relu] -------------
// A bf16 [M][K], Bt bf16 [Nc][K] (pre-transposed W). BM=64, BN=128, BK=64.
template <bool RELU, bool RES, bool OUTBF>
__global__ __launch_bounds__(256) void k_mgemm(const unsigned short* __restrict__ A,
                                               const unsigned short* __restrict__ Bt,
                                               const float* __restrict__ bias,
                                               const float* __restrict__ res,
                                               void* __restrict__ outp,
                                               int K, int Nc) {
  __shared__ unsigned short As[64 * 64];    // [r][slot] 8 KB, slot-swizzled
  __shared__ unsigned short Bs[128 * 64];   // [n][slot] 16 KB, slot-swizzled
  const int tid  = threadIdx.x;
  const int row0 = blockIdx.x * 64;
  const int c0   = blockIdx.y * 128;
  const int l    = tid & 63;
  const int w    = tid >> 6;
  const int wr   = w >> 1;   // 0..1 (32-row half)
  const int wc   = w & 1;    // 0..1 (64-col half)

  f32x4 acc[2][4] = {};

  for (int kc = 0; kc < K; kc += 64) {
    __syncthreads();
    #pragma unroll
    for (int it = 0; it < 2; it++) {       // A: 512 x 16B slots
      int idx = it * 256 + tid;
      int r = idx >> 3, s = idx & 7;
      uint4 vv = *(const uint4*)(A + (size_t)(row0 + r) * K + kc + s * 8);
      *(uint4*)(As + r * 64 + ((s ^ (r & 7)) * 8)) = vv;
    }
    #pragma unroll
    for (int it = 0; it < 4; it++) {       // B: 1024 x 16B slots
      int idx = it * 256 + tid;
      int n = idx >> 3, s = idx & 7;
      uint4 vv = *(const uint4*)(Bt + (size_t)(c0 + n) * K + kc + s * 8);
      *(uint4*)(Bs + n * 64 + ((s ^ (n & 7)) * 8)) = vv;
    }
    __syncthreads();
    #pragma unroll
    for (int kk = 0; kk < 2; kk++) {
      int sb = kk * 4 + (l >> 4);          // logical 16B slot for this lane
      bf16x8 af[2], bfr[4];
      #pragma unroll
      for (int mi = 0; mi < 2; mi++) {
        int r = wr * 32 + mi * 16 + (l & 15);
        af[mi] = *(const bf16x8*)(As + r * 64 + ((sb ^ (r & 7)) * 8));
      }
      #pragma unroll
      for (int ni = 0; ni < 4; ni++) {
        int n = wc * 64 + ni * 16 + (l & 15);
        bfr[ni] = *(const bf16x8*)(Bs + n * 64 + ((sb ^ (n & 7)) * 8));
      }
      #pragma unroll
      for (int mi = 0; mi < 2; mi++)
        #pragma unroll
        for (int ni = 0; ni < 4; ni++)
          acc[mi][ni] = __builtin_amdgcn_mfma_f32_16x16x32_bf16(af[mi], bfr[ni], acc[mi][ni], 0, 0, 0);
    }
  }

  // epilogue: C row = (l>>4)*4 + p, col = l&15 within each 16x16 frag
  #pragma unroll
  for (int mi = 0; mi < 2; mi++) {
    #pragma unroll
    for (int p = 0; p < 4; p++) {
      int r = row0 + wr * 32 + mi * 16 + (l >> 4) * 4 + p;
      #pragma unroll
      for (int ni = 0; ni < 4; ni++) {
        int c = c0 + wc * 64 + ni * 16 + (l & 15);
        float val = acc[mi][ni][p] + bias[c];
        if (RES)  val += res[(size_t)r * Nc + c];
        if (RELU) val = fmaxf(val, 0.f);
        if (OUTBF) ((unsigned short*)outp)[(size_t)r * Nc + c] = f2bf(val);
        else       ((float*)outp)[(size_t)r * Nc + c] = val;
      }
    }
  }
}

// ---------------- Edge scores + exp + per-head partial sums ----------------
__global__ __launch_bounds__(256) void k_scores(const unsigned short* __restrict__ q,
                                                const unsigned short* __restrict__ k,
                                                const int* __restrict__ ei,
                                                float* __restrict__ wscore,
                                                float* __restrict__ hpartial) {
  const int tid  = threadIdx.x;
  const int gid0 = blockIdx.x * 256 + tid;
  const int total = NEDGE * NH;
  float lsum = 0.f;
  for (int gid = gid0; gid < total; gid += SGRID * 256) {
    int e = gid >> 3;
    int h = gid & 7;
    int src = ei[e];
    int dst = ei[NEDGE + e];
    const uint4* qr = (const uint4*)(q + (size_t)dst * CCH + h * HD);
    const uint4* kr = (const uint4*)(k + (size_t)src * CCH + h * HD);
    float s = 0.f;
    #pragma unroll
    for (int i = 0; i < 2; i++) {
      uint4 a = qr[i], bb = kr[i];
      s += bflo(a.x) * bflo(bb.x) + bfhi(a.x) * bfhi(bb.x);
      s += bflo(a.y) * bflo(bb.y) + bfhi(a.y) * bfhi(bb.y);
      s += bflo(a.z) * bflo(bb.z) + bfhi(a.z) * bfhi(bb.z);
      s += bflo(a.w) * bflo(bb.w) + bfhi(a.w) * bfhi(bb.w);
    }
    float es = __expf(s * 0.25f);
    wscore[gid] = es;
    lsum += es;
  }
  #pragma unroll
  for (int d = 8; d < 64; d <<= 1) lsum += __shfl_xor(lsum, d);
  __shared__ float wsum[4][8];
  int lane = tid & 63, wv = tid >> 6;
  if (lane < 8) wsum[wv][lane] = lsum;
  __syncthreads();
  if (tid < 8) {
    hpartial[blockIdx.x * 8 + tid] =
        wsum[0][tid] + wsum[1][tid] + wsum[2][tid] + wsum[3][tid];
  }
}

__global__ __launch_bounds__(256) void k_reduce_inv(const float* __restrict__ hpartial,
                                                    float* __restrict__ inv) {
  const int tid = threadIdx.x;
  const int h = tid & 7;
  float s = 0.f;
  for (int i = tid >> 3; i < SGRID; i += 32) s += hpartial[i * 8 + h];
  #pragma unroll
  for (int d = 8; d < 64; d <<= 1) s += __shfl_xor(s, d);
  __shared__ float wsum[4][8];
  int lane = tid & 63, wv = tid >> 6;
  if (lane < 8) wsum[wv][lane] = s;
  __syncthreads();
  if (tid < 8) {
    float t = wsum[0][tid] + wsum[1][tid] + wsum[2][tid] + wsum[3][tid];
    inv[tid] = 1.0f / t;
  }
}

// ---------------- CSR build: histogram -> 3-stage scan -> scatter ----------
__global__ __launch_bounds__(256) void k_hist(const int* __restrict__ ei,
                                              int* __restrict__ deg) {
  int e = blockIdx.x * 256 + threadIdx.x;
  if (e >= NEDGE) return;
  atomicAdd(&deg[ei[NEDGE + e]], 1);
}

__global__ __launch_bounds__(256) void k_scan3a(const int* __restrict__ deg,
                                                int* __restrict__ bsum) {
  int i = blockIdx.x * 256 + threadIdx.x;
  int d = (i < NNODES) ? deg[i] : 0;
  #pragma unroll
  for (int s = 1; s < 64; s <<= 1) d += __shfl_xor(d, s);
  __shared__ int ws4[4];
  if ((threadIdx.x & 63) == 0) ws4[threadIdx.x >> 6] = d;
  __syncthreads();
  if (threadIdx.x == 0) bsum[blockIdx.x] = ws4[0] + ws4[1] + ws4[2] + ws4[3];
}

__global__ __launch_bounds__(256) void k_scan3b(const int* __restrict__ bsum,
                                                int* __restrict__ bpre) {
  int t = threadIdx.x;
  int d = (t < NBLK) ? bsum[t] : 0;
  int lane = t & 63, wv = t >> 6;
  int incl = d;
  #pragma unroll
  for (int s = 1; s < 64; s <<= 1) { int o = __shfl_up(incl, s); if (lane >= s) incl += o; }
  __shared__ int wsum[4];
  if (lane == 63) wsum[wv] = incl;
  __syncthreads();
  int base = 0;
  for (int w2 = 0; w2 < wv; w2++) base += wsum[w2];
  if (t < NBLK) bpre[t] = base + incl - d;
}

__global__ __launch_bounds__(256) void k_scan3c(const int* __restrict__ deg,
                                                const int* __restrict__ bpre,
                                                int* __restrict__ off,
                                                int* __restrict__ cursor) {
  int t = threadIdx.x;
  int i = blockIdx.x * 256 + t;
  int d = (i < NNODES) ? deg[i] : 0;
  int lane = t & 63, wv = t >> 6;
  int incl = d;
  #pragma unroll
  for (int s = 1; s < 64; s <<= 1) { int o = __shfl_up(incl, s); if (lane >= s) incl += o; }
  __shared__ int wsum[4];
  if (lane == 63) wsum[wv] = incl;
  __syncthreads();
  int base = bpre[blockIdx.x];
  for (int w2 = 0; w2 < wv; w2++) base += wsum[w2];
  int ex = base + incl - d;
  if (i < NNODES) { off[i] = ex; cursor[i] = ex; }
  if (i == 0) off[NNODES] = NEDGE;
}

__global__ __launch_bounds__(256) void k_scatter(const int* __restrict__ ei,
                                                 int* __restrict__ cursor,
                                                 int* __restrict__ sorted,
                                                 int* __restrict__ srcs) {
  int e = blockIdx.x * 256 + threadIdx.x;
  if (e >= NEDGE) return;
  int src = ei[e];
  int pos = atomicAdd(&cursor[ei[NEDGE + e]], 1);
  sorted[pos] = e;
  srcs[pos] = src;
}

// ---------------- Gather aggregation: 1 wave per dst node, bf16 out -------
__global__ __launch_bounds__(256) void k_agg2(const unsigned short* __restrict__ v,
                                              const float* __restrict__ wscore,
                                              const float* __restrict__ inv,
                                              const int* __restrict__ off,
                                              const int* __restrict__ sorted,
                                              const int* __restrict__ srcs,
                                              unsigned* __restrict__ agg) {
  int wave = threadIdx.x >> 6;
  int lane = threadIdx.x & 63;
  int n = blockIdx.x * 4 + wave;
  if (n >= NNODES) return;
  int h = lane >> 3;
  float winv = inv[h];
  float ax = 0.f, ay = 0.f;
  int i0 = off[n], i1 = off[n + 1];
  for (int i = i0; i < i1; i += 64) {
    int cnt = i1 - i; if (cnt > 64) cnt = 64;
    int e_l = (i + lane < i1) ? sorted[i + lane] : 0;
    int s_l = (i + lane < i1) ? srcs[i + lane] : 0;
    for (int j = 0; j < cnt; j++) {
      int e   = __shfl(e_l, j);
      int src = __shfl(s_l, j);
      float w = wscore[(size_t)e * NH + h] * winv;
      unsigned uv = *(const unsigned*)(v + (size_t)src * CCH + lane * 2);
      ax += w * bflo(uv);
      ay += w * bfhi(uv);
    }
  }
  agg[(size_t)n * 64 + lane] = ((unsigned)f2bf(ay) << 16) | f2bf(ax);
}

extern "C" void kernel_launch(void* const* d_in, const int* in_sizes, int n_in,
                              void* d_out, int out_size, void* d_ws, size_t ws_size,
                              hipStream_t stream) {
  const float* x    = (const float*)d_in[0];
  const int*   ei   = (const int*)d_in[1];
  const float* Wq   = (const float*)d_in[2];
  const float* bq   = (const float*)d_in[3];
  const float* Wk   = (const float*)d_in[4];
  const float* bk   = (const float*)d_in[5];
  const float* Wv   = (const float*)d_in[6];
  const float* bv   = (const float*)d_in[7];
  const float* Wo   = (const float*)d_in[8];
  const float* bo   = (const float*)d_in[9];
  const float* ln1g = (const float*)d_in[10];
  const float* ln1b = (const float*)d_in[11];
  const float* ln2g = (const float*)d_in[12];
  const float* ln2b = (const float*)d_in[13];
  const float* W1   = (const float*)d_in[14];
  const float* b1   = (const float*)d_in[15];
  const float* W2   = (const float*)d_in[16];
  const float* b2   = (const float*)d_in[17];
  float* out = (float*)d_out;

  char* base = (char*)d_ws;
  const size_t NCb = (size_t)NNODES * CCH * 2;       // bf16 activation: 10.24 MB
  unsigned short* xn     = (unsigned short*)(base);            // buf0; later xn2
  unsigned short* q      = (unsigned short*)(base + 1 * NCb);  // buf1; later agg
  unsigned short* kk     = (unsigned short*)(base + 2 * NCb);  // buf2
  unsigned short* vv     = (unsigned short*)(base + 3 * NCb);  // buf3
  float*          wscore = (float*)(base + 4 * NCb);           // 20.48 MB
  unsigned short* ffn1   = (unsigned short*)(base + 2 * NCb);  // overlays kk,vv,wscore (40.96 MB)
  float*          x1     = (float*)(base + 4 * NCb + (size_t)NEDGE * NH * 4);  // 20.48 MB
  char* aux = base + 4 * NCb + (size_t)NEDGE * NH * 4 + (size_t)NNODES * CCH * 4;
  int* deg    = (int*)aux;                     aux += (size_t)NNODES * 4 + 256;
  int* off    = (int*)aux;                     aux += (size_t)(NNODES + 1) * 4 + 256;
  int* cursor = (int*)aux;                     aux += (size_t)NNODES * 4 + 256;
  int* sorted = (int*)aux;                     aux += (size_t)NEDGE * 4;
  int* srcs   = (int*)aux;                     aux += (size_t)NEDGE * 4;
  int* bsum   = (int*)aux;                     aux += 256 * 4;
  int* bpre   = (int*)aux;                     aux += 256 * 4;
  float* hpart = (float*)aux;                  aux += (size_t)SGRID * 8 * 4;
  float* inv   = (float*)aux;                  aux += 64;
  unsigned short* Wqt = (unsigned short*)aux;  aux += (size_t)CCH * CCH * 2;
  unsigned short* Wkt = (unsigned short*)aux;  aux += (size_t)CCH * CCH * 2;
  unsigned short* Wvt = (unsigned short*)aux;  aux += (size_t)CCH * CCH * 2;
  unsigned short* Wot = (unsigned short*)aux;  aux += (size_t)CCH * CCH * 2;
  unsigned short* W1t = (unsigned short*)aux;  aux += (size_t)CCH * 4 * CCH * 2;
  unsigned short* W2t = (unsigned short*)aux;  aux += (size_t)CCH * 4 * CCH * 2;
  unsigned short* agg = q;      // overlays q (dead after k_scores)
  unsigned short* xn2 = xn;     // overlays xn (dead after QKV)

  dim3 blk(256);
  dim3 gLN(NNODES / 4);
  dim3 gM(NNODES / 64, 1);
  dim3 gM4(NNODES / 64, 4);
  dim3 gE((NEDGE + 255) / 256);
  dim3 gW64((CCH * CCH + 255) / 256);
  dim3 gW256((CCH * 4 * CCH + 255) / 256);

  // CSR build (depends only on ei)
  hipMemsetAsync(deg, 0, (size_t)NNODES * 4, stream);
  k_hist<<<gE, blk, 0, stream>>>(ei, deg);
  k_scan3a<<<NBLK, blk, 0, stream>>>(deg, bsum);
  k_scan3b<<<1, blk, 0, stream>>>(bsum, bpre);
  k_scan3c<<<NBLK, blk, 0, stream>>>(deg, bpre, off, cursor);
  k_scatter<<<gE, blk, 0, stream>>>(ei, cursor, sorted, srcs);

  // weight prep (transpose + bf16)
  k_wprep<<<gW64, blk, 0, stream>>>(Wq, Wqt, CCH, CCH);
  k_wprep<<<gW64, blk, 0, stream>>>(Wk, Wkt, CCH, CCH);
  k_wprep<<<gW64, blk, 0, stream>>>(Wv, Wvt, CCH, CCH);
  k_wprep<<<gW64, blk, 0, stream>>>(Wo, Wot, CCH, CCH);
  k_wprep<<<gW256, blk, 0, stream>>>(W1, W1t, CCH, 4 * CCH);
  k_wprep<<<gW256, blk, 0, stream>>>(W2, W2t, 4 * CCH, CCH);

  // LN1 + QKV (bf16 MFMA)
  k_ln_bf<<<gLN, blk, 0, stream>>>(x, ln1g, ln1b, (unsigned*)xn);
  k_mgemm<false, false, true><<<gM, blk, 0, stream>>>(xn, Wqt, bq, nullptr, q,  CCH, CCH);
  k_mgemm<false, false, true><<<gM, blk, 0, stream>>>(xn, Wkt, bk, nullptr, kk, CCH, CCH);
  k_mgemm<false, false, true><<<gM, blk, 0, stream>>>(xn, Wvt, bv, nullptr, vv, CCH, CCH);

  // edge scores -> exp + global-softmax denominator
  k_scores<<<SGRID, blk, 0, stream>>>(q, kk, ei, wscore, hpart);
  k_reduce_inv<<<1, blk, 0, stream>>>(hpart, inv);

  // gather aggregation -> agg (bf16, overlays q)
  k_agg2<<<gLN, blk, 0, stream>>>(vv, wscore, inv, off, sorted, srcs, (unsigned*)agg);

  // out-proj + residual -> x1 (fp32)
  k_mgemm<false, true, false><<<gM, blk, 0, stream>>>(agg, Wot, bo, x, x1, CCH, CCH);
  // LN2 -> xn2 (bf16, overlays xn)
  k_ln_bf<<<gLN, blk, 0, stream>>>(x1, ln2g, ln2b, (unsigned*)xn2);
  // FFN1 (relu, bf16 out, overlays kk/vv/wscore)
  k_mgemm<true, false, true><<<gM4, blk, 0, stream>>>(xn2, W1t, b1, nullptr, ffn1, CCH, 4 * CCH);
  // FFN2 (+residual x1) -> d_out fp32
  k_mgemm<false, true, false><<<gM, blk, 0, stream>>>(ffn1, W2t, b2, x1, out, 4 * CCH, CCH);
}

// Round 4
// 248.844 us; speedup vs baseline: 19.9642x; 1.1342x over previous
//
#include <hip/hip_runtime.h>
#include <math.h>

#define NNODES 40000
#define CCH    128
#define NH     8
#define HD     16
#define NEDGE  640000
#define SGRID  2048
#define NBLK   157   // ceil(NNODES/256)

typedef __attribute__((ext_vector_type(8))) short bf16x8;
typedef __attribute__((ext_vector_type(4))) float f32x4;

__device__ inline unsigned short f2bf(float f) {
  union { float f; unsigned u; } c; c.f = f;
  unsigned r = c.u + 0x7fffu + ((c.u >> 16) & 1u);
  return (unsigned short)(r >> 16);
}
__device__ inline float bflo(unsigned u) { union { unsigned i; float f; } c; c.i = u << 16; return c.f; }
__device__ inline float bfhi(unsigned u) { union { unsigned i; float f; } c; c.i = u & 0xffff0000u; return c.f; }

// ---------------- LayerNorm: 4 waves/block, 1 row/wave, bf16 out ----------
__global__ __launch_bounds__(256) void k_ln_bf(const float* __restrict__ x,
                                               const float* __restrict__ g,
                                               const float* __restrict__ b,
                                               unsigned* __restrict__ out) {
  int wave = threadIdx.x >> 6;
  int lane = threadIdx.x & 63;
  int row  = blockIdx.x * 4 + wave;
  if (row >= NNODES) return;
  const float2* xr = (const float2*)(x + (size_t)row * CCH);
  float2 v = xr[lane];
  float s  = v.x + v.y;
  float ss = v.x * v.x + v.y * v.y;
  #pragma unroll
  for (int d = 1; d < 64; d <<= 1) {
    s  += __shfl_xor(s, d);
    ss += __shfl_xor(ss, d);
  }
  float mean = s * (1.0f / CCH);
  float var  = ss * (1.0f / CCH) - mean * mean;
  float rstd = rsqrtf(var + 1e-5f);
  float2 gg = ((const float2*)g)[lane];
  float2 bb = ((const float2*)b)[lane];
  float ox = (v.x - mean) * rstd * gg.x + bb.x;
  float oy = (v.y - mean) * rstd * gg.y + bb.y;
  out[(size_t)row * 64 + lane] = ((unsigned)f2bf(oy) << 16) | f2bf(ox);
}

// ---------------- Weight prep: transpose + bf16 convert -------------------
__global__ __launch_bounds__(256) void k_wprep(const float* __restrict__ W,
                                               unsigned short* __restrict__ Wt,
                                               int K, int Nc) {
  int idx = blockIdx.x * 256 + threadIdx.x;
  if (idx >= K * Nc) return;
  int n = idx / K, k = idx - n * K;
  Wt[idx] = f2bf(W[(size_t)k * Nc + n]);
}

// ---------------- MFMA GEMM: out = [res +] A@W + bias [,relu] -------------
template <bool RELU, bool RES, bool OUTBF>
__global__ __launch_bounds__(256) void k_mgemm(const unsigned short* __restrict__ A,
                                               const unsigned short* __restrict__ Bt,
                                               const float* __restrict__ bias,
                                               const float* __restrict__ res,
                                               void* __restrict__ outp,
                                               int K, int Nc) {
  __shared__ unsigned short As[64 * 64];
  __shared__ unsigned short Bs[128 * 64];
  const int tid  = threadIdx.x;
  const int row0 = blockIdx.x * 64;
  const int c0   = blockIdx.y * 128;
  const int l    = tid & 63;
  const int w    = tid >> 6;
  const int wr   = w >> 1;
  const int wc   = w & 1;

  f32x4 acc[2][4] = {};

  for (int kc = 0; kc < K; kc += 64) {
    __syncthreads();
    #pragma unroll
    for (int it = 0; it < 2; it++) {
      int idx = it * 256 + tid;
      int r = idx >> 3, s = idx & 7;
      uint4 vv = *(const uint4*)(A + (size_t)(row0 + r) * K + kc + s * 8);
      *(uint4*)(As + r * 64 + ((s ^ (r & 7)) * 8)) = vv;
    }
    #pragma unroll
    for (int it = 0; it < 4; it++) {
      int idx = it * 256 + tid;
      int n = idx >> 3, s = idx & 7;
      uint4 vv = *(const uint4*)(Bt + (size_t)(c0 + n) * K + kc + s * 8);
      *(uint4*)(Bs + n * 64 + ((s ^ (n & 7)) * 8)) = vv;
    }
    __syncthreads();
    #pragma unroll
    for (int kk = 0; kk < 2; kk++) {
      int sb = kk * 4 + (l >> 4);
      bf16x8 af[2], bfr[4];
      #pragma unroll
      for (int mi = 0; mi < 2; mi++) {
        int r = wr * 32 + mi * 16 + (l & 15);
        af[mi] = *(const bf16x8*)(As + r * 64 + ((sb ^ (r & 7)) * 8));
      }
      #pragma unroll
      for (int ni = 0; ni < 4; ni++) {
        int n = wc * 64 + ni * 16 + (l & 15);
        bfr[ni] = *(const bf16x8*)(Bs + n * 64 + ((sb ^ (n & 7)) * 8));
      }
      #pragma unroll
      for (int mi = 0; mi < 2; mi++)
        #pragma unroll
        for (int ni = 0; ni < 4; ni++)
          acc[mi][ni] = __builtin_amdgcn_mfma_f32_16x16x32_bf16(af[mi], bfr[ni], acc[mi][ni], 0, 0, 0);
    }
  }

  #pragma unroll
  for (int mi = 0; mi < 2; mi++) {
    #pragma unroll
    for (int p = 0; p < 4; p++) {
      int r = row0 + wr * 32 + mi * 16 + (l >> 4) * 4 + p;
      #pragma unroll
      for (int ni = 0; ni < 4; ni++) {
        int c = c0 + wc * 64 + ni * 16 + (l & 15);
        float val = acc[mi][ni][p] + bias[c];
        if (RES)  val += res[(size_t)r * Nc + c];
        if (RELU) val = fmaxf(val, 0.f);
        if (OUTBF) ((unsigned short*)outp)[(size_t)r * Nc + c] = f2bf(val);
        else       ((float*)outp)[(size_t)r * Nc + c] = val;
      }
    }
  }
}

// ------- Edge scores in dst-sorted order: coalesced wsorted writes --------
__global__ __launch_bounds__(256) void k_scores(const unsigned short* __restrict__ q,
                                                const unsigned short* __restrict__ k,
                                                const int* __restrict__ srcs,
                                                const int* __restrict__ dsts,
                                                float* __restrict__ wsorted,
                                                float* __restrict__ hpartial) {
  const int tid  = threadIdx.x;
  const int gid0 = blockIdx.x * 256 + tid;
  const int total = NEDGE * NH;
  float lsum = 0.f;
  for (int gid = gid0; gid < total; gid += SGRID * 256) {
    int p = gid >> 3;
    int h = gid & 7;
    int src = srcs[p];
    int dst = dsts[p];
    const uint4* qr = (const uint4*)(q + (size_t)dst * CCH + h * HD);
    const uint4* kr = (const uint4*)(k + (size_t)src * CCH + h * HD);
    float s = 0.f;
    #pragma unroll
    for (int i = 0; i < 2; i++) {
      uint4 a = qr[i], bb = kr[i];
      s += bflo(a.x) * bflo(bb.x) + bfhi(a.x) * bfhi(bb.x);
      s += bflo(a.y) * bflo(bb.y) + bfhi(a.y) * bfhi(bb.y);
      s += bflo(a.z) * bflo(bb.z) + bfhi(a.z) * bfhi(bb.z);
      s += bflo(a.w) * bflo(bb.w) + bfhi(a.w) * bfhi(bb.w);
    }
    float es = __expf(s * 0.25f);
    wsorted[gid] = es;
    lsum += es;
  }
  #pragma unroll
  for (int d = 8; d < 64; d <<= 1) lsum += __shfl_xor(lsum, d);
  __shared__ float wsum[4][8];
  int lane = tid & 63, wv = tid >> 6;
  if (lane < 8) wsum[wv][lane] = lsum;
  __syncthreads();
  if (tid < 8) {
    hpartial[blockIdx.x * 8 + tid] =
        wsum[0][tid] + wsum[1][tid] + wsum[2][tid] + wsum[3][tid];
  }
}

__global__ __launch_bounds__(256) void k_reduce_inv(const float* __restrict__ hpartial,
                                                    float* __restrict__ inv) {
  const int tid = threadIdx.x;
  const int h = tid & 7;
  float s = 0.f;
  for (int i = tid >> 3; i < SGRID; i += 32) s += hpartial[i * 8 + h];
  #pragma unroll
  for (int d = 8; d < 64; d <<= 1) s += __shfl_xor(s, d);
  __shared__ float wsum[4][8];
  int lane = tid & 63, wv = tid >> 6;
  if (lane < 8) wsum[wv][lane] = s;
  __syncthreads();
  if (tid < 8) {
    float t = wsum[0][tid] + wsum[1][tid] + wsum[2][tid] + wsum[3][tid];
    inv[tid] = 1.0f / t;
  }
}

// ---------------- CSR build: histogram -> 3-stage scan -> scatter ----------
__global__ __launch_bounds__(256) void k_hist(const int* __restrict__ ei,
                                              int* __restrict__ deg) {
  int e = blockIdx.x * 256 + threadIdx.x;
  if (e >= NEDGE) return;
  atomicAdd(&deg[ei[NEDGE + e]], 1);
}

__global__ __launch_bounds__(256) void k_scan3a(const int* __restrict__ deg,
                                                int* __restrict__ bsum) {
  int i = blockIdx.x * 256 + threadIdx.x;
  int d = (i < NNODES) ? deg[i] : 0;
  #pragma unroll
  for (int s = 1; s < 64; s <<= 1) d += __shfl_xor(d, s);
  __shared__ int ws4[4];
  if ((threadIdx.x & 63) == 0) ws4[threadIdx.x >> 6] = d;
  __syncthreads();
  if (threadIdx.x == 0) bsum[blockIdx.x] = ws4[0] + ws4[1] + ws4[2] + ws4[3];
}

__global__ __launch_bounds__(256) void k_scan3b(const int* __restrict__ bsum,
                                                int* __restrict__ bpre) {
  int t = threadIdx.x;
  int d = (t < NBLK) ? bsum[t] : 0;
  int lane = t & 63, wv = t >> 6;
  int incl = d;
  #pragma unroll
  for (int s = 1; s < 64; s <<= 1) { int o = __shfl_up(incl, s); if (lane >= s) incl += o; }
  __shared__ int wsum[4];
  if (lane == 63) wsum[wv] = incl;
  __syncthreads();
  int base = 0;
  for (int w2 = 0; w2 < wv; w2++) base += wsum[w2];
  if (t < NBLK) bpre[t] = base + incl - d;
}

__global__ __launch_bounds__(256) void k_scan3c(const int* __restrict__ deg,
                                                const int* __restrict__ bpre,
                                                int* __restrict__ off,
                                                int* __restrict__ cursor) {
  int t = threadIdx.x;
  int i = blockIdx.x * 256 + t;
  int d = (i < NNODES) ? deg[i] : 0;
  int lane = t & 63, wv = t >> 6;
  int incl = d;
  #pragma unroll
  for (int s = 1; s < 64; s <<= 1) { int o = __shfl_up(incl, s); if (lane >= s) incl += o; }
  __shared__ int wsum[4];
  if (lane == 63) wsum[wv] = incl;
  __syncthreads();
  int base = bpre[blockIdx.x];
  for (int w2 = 0; w2 < wv; w2++) base += wsum[w2];
  int ex = base + incl - d;
  if (i < NNODES) { off[i] = ex; cursor[i] = ex; }
  if (i == 0) off[NNODES] = NEDGE;
}

__global__ __launch_bounds__(256) void k_scatter(const int* __restrict__ ei,
                                                 int* __restrict__ cursor,
                                                 int* __restrict__ srcs,
                                                 int* __restrict__ dsts) {
  int e = blockIdx.x * 256 + threadIdx.x;
  if (e >= NEDGE) return;
  int src = ei[e];
  int dst = ei[NEDGE + e];
  int pos = atomicAdd(&cursor[dst], 1);
  srcs[pos] = src;
  dsts[pos] = dst;
}

// ------- Gather aggregation: 1 wave per dst, 4 edges in flight ------------
__global__ __launch_bounds__(256) void k_agg2(const unsigned short* __restrict__ v,
                                              const float* __restrict__ wsorted,
                                              const float* __restrict__ inv,
                                              const int* __restrict__ off,
                                              const int* __restrict__ srcs,
                                              unsigned* __restrict__ agg) {
  int wave = threadIdx.x >> 6;
  int lane = threadIdx.x & 63;
  int n = blockIdx.x * 4 + wave;
  if (n >= NNODES) return;
  int g   = lane >> 4;   // edge sub-group 0..3
  int c16 = lane & 15;   // channel group: channels c16*8 .. c16*8+7
  int h   = c16 >> 1;    // head for these channels
  float winv = inv[h];
  float a0 = 0.f, a1 = 0.f, a2 = 0.f, a3 = 0.f, a4 = 0.f, a5 = 0.f, a6 = 0.f, a7 = 0.f;
  int i0 = off[n], i1 = off[n + 1];
  for (int i = i0; i < i1; i += 64) {
    int s_l = (i + lane < i1) ? srcs[i + lane] : 0;
    int cnt = i1 - i; if (cnt > 64) cnt = 64;
    for (int j = 0; j < cnt; j += 4) {
      int src = __shfl(s_l, j + g);
      float w = (j + g < cnt) ? wsorted[(size_t)(i + j + g) * NH + h] * winv : 0.f;
      uint4 uv = *(const uint4*)(v + (size_t)src * CCH + c16 * 8);
      a0 += w * bflo(uv.x); a1 += w * bfhi(uv.x);
      a2 += w * bflo(uv.y); a3 += w * bfhi(uv.y);
      a4 += w * bflo(uv.z); a5 += w * bfhi(uv.z);
      a6 += w * bflo(uv.w); a7 += w * bfhi(uv.w);
    }
  }
  #pragma unroll
  for (int d = 16; d < 64; d <<= 1) {
    a0 += __shfl_xor(a0, d); a1 += __shfl_xor(a1, d);
    a2 += __shfl_xor(a2, d); a3 += __shfl_xor(a3, d);
    a4 += __shfl_xor(a4, d); a5 += __shfl_xor(a5, d);
    a6 += __shfl_xor(a6, d); a7 += __shfl_xor(a7, d);
  }
  if (lane < 16) {
    uint4 o;
    o.x = ((unsigned)f2bf(a1) << 16) | f2bf(a0);
    o.y = ((unsigned)f2bf(a3) << 16) | f2bf(a2);
    o.z = ((unsigned)f2bf(a5) << 16) | f2bf(a4);
    o.w = ((unsigned)f2bf(a7) << 16) | f2bf(a6);
    *(uint4*)(agg + (size_t)n * 64 + c16 * 4) = o;
  }
}

extern "C" void kernel_launch(void* const* d_in, const int* in_sizes, int n_in,
                              void* d_out, int out_size, void* d_ws, size_t ws_size,
                              hipStream_t stream) {
  const float* x    = (const float*)d_in[0];
  const int*   ei   = (const int*)d_in[1];
  const float* Wq   = (const float*)d_in[2];
  const float* bq   = (const float*)d_in[3];
  const float* Wk   = (const float*)d_in[4];
  const float* bk   = (const float*)d_in[5];
  const float* Wv   = (const float*)d_in[6];
  const float* bv   = (const float*)d_in[7];
  const float* Wo   = (const float*)d_in[8];
  const float* bo   = (const float*)d_in[9];
  const float* ln1g = (const float*)d_in[10];
  const float* ln1b = (const float*)d_in[11];
  const float* ln2g = (const float*)d_in[12];
  const float* ln2b = (const float*)d_in[13];
  const float* W1   = (const float*)d_in[14];
  const float* b1   = (const float*)d_in[15];
  const float* W2   = (const float*)d_in[16];
  const float* b2   = (const float*)d_in[17];
  float* out = (float*)d_out;

  char* base = (char*)d_ws;
  const size_t NCb = (size_t)NNODES * CCH * 2;       // bf16 activation: 10.24 MB
  unsigned short* xn      = (unsigned short*)(base);
  unsigned short* q       = (unsigned short*)(base + 1 * NCb);
  unsigned short* kk      = (unsigned short*)(base + 2 * NCb);
  unsigned short* vv      = (unsigned short*)(base + 3 * NCb);
  float*          wsorted = (float*)(base + 4 * NCb);                       // 20.48 MB
  unsigned short* ffn1    = (unsigned short*)(base + 2 * NCb);              // overlays kk,vv,wsorted
  float*          x1      = (float*)(base + 4 * NCb + (size_t)NEDGE * NH * 4);
  char* aux = base + 4 * NCb + (size_t)NEDGE * NH * 4 + (size_t)NNODES * CCH * 4;
  int* deg    = (int*)aux;                     aux += (size_t)NNODES * 4 + 256;
  int* off    = (int*)aux;                     aux += (size_t)(NNODES + 1) * 4 + 256;
  int* cursor = (int*)aux;                     aux += (size_t)NNODES * 4 + 256;
  int* srcs   = (int*)aux;                     aux += (size_t)NEDGE * 4;
  int* dsts   = (int*)aux;                     aux += (size_t)NEDGE * 4;
  int* bsum   = (int*)aux;                     aux += 256 * 4;
  int* bpre   = (int*)aux;                     aux += 256 * 4;
  float* hpart = (float*)aux;                  aux += (size_t)SGRID * 8 * 4;
  float* inv   = (float*)aux;                  aux += 64;
  unsigned short* Wqt = (unsigned short*)aux;  aux += (size_t)CCH * CCH * 2;
  unsigned short* Wkt = (unsigned short*)aux;  aux += (size_t)CCH * CCH * 2;
  unsigned short* Wvt = (unsigned short*)aux;  aux += (size_t)CCH * CCH * 2;
  unsigned short* Wot = (unsigned short*)aux;  aux += (size_t)CCH * CCH * 2;
  unsigned short* W1t = (unsigned short*)aux;  aux += (size_t)CCH * 4 * CCH * 2;
  unsigned short* W2t = (unsigned short*)aux;  aux += (size_t)CCH * 4 * CCH * 2;
  unsigned short* agg = q;
  unsigned short* xn2 = xn;

  dim3 blk(256);
  dim3 gLN(NNODES / 4);
  dim3 gM(NNODES / 64, 1);
  dim3 gM4(NNODES / 64, 4);
  dim3 gE((NEDGE + 255) / 256);
  dim3 gW64((CCH * CCH + 255) / 256);
  dim3 gW256((CCH * 4 * CCH + 255) / 256);

  // CSR build (depends only on ei)
  hipMemsetAsync(deg, 0, (size_t)NNODES * 4, stream);
  k_hist<<<gE, blk, 0, stream>>>(ei, deg);
  k_scan3a<<<NBLK, blk, 0, stream>>>(deg, bsum);
  k_scan3b<<<1, blk, 0, stream>>>(bsum, bpre);
  k_scan3c<<<NBLK, blk, 0, stream>>>(deg, bpre, off, cursor);
  k_scatter<<<gE, blk, 0, stream>>>(ei, cursor, srcs, dsts);

  // weight prep (transpose + bf16)
  k_wprep<<<gW64, blk, 0, stream>>>(Wq, Wqt, CCH, CCH);
  k_wprep<<<gW64, blk, 0, stream>>>(Wk, Wkt, CCH, CCH);
  k_wprep<<<gW64, blk, 0, stream>>>(Wv, Wvt, CCH, CCH);
  k_wprep<<<gW64, blk, 0, stream>>>(Wo, Wot, CCH, CCH);
  k_wprep<<<gW256, blk, 0, stream>>>(W1, W1t, CCH, 4 * CCH);
  k_wprep<<<gW256, blk, 0, stream>>>(W2, W2t, 4 * CCH, CCH);

  // LN1 + QKV (bf16 MFMA)
  k_ln_bf<<<gLN, blk, 0, stream>>>(x, ln1g, ln1b, (unsigned*)xn);
  k_mgemm<false, false, true><<<gM, blk, 0, stream>>>(xn, Wqt, bq, nullptr, q,  CCH, CCH);
  k_mgemm<false, false, true><<<gM, blk, 0, stream>>>(xn, Wkt, bk, nullptr, kk, CCH, CCH);
  k_mgemm<false, false, true><<<gM, blk, 0, stream>>>(xn, Wvt, bv, nullptr, vv, CCH, CCH);

  // edge scores in sorted order -> coalesced wsorted + denominator
  k_scores<<<SGRID, blk, 0, stream>>>(q, kk, srcs, dsts, wsorted, hpart);
  k_reduce_inv<<<1, blk, 0, stream>>>(hpart, inv);

  // gather aggregation -> agg (bf16, overlays q)
  k_agg2<<<gLN, blk, 0, stream>>>(vv, wsorted, inv, off, srcs, (unsigned*)agg);

  // out-proj + residual -> x1 (fp32)
  k_mgemm<false, true, false><<<gM, blk, 0, stream>>>(agg, Wot, bo, x, x1, CCH, CCH);
  // LN2 -> xn2 (bf16, overlays xn)
  k_ln_bf<<<gLN, blk, 0, stream>>>(x1, ln2g, ln2b, (unsigned*)xn2);
  // FFN1 (relu, bf16 out)
  k_mgemm<true, false, true><<<gM4, blk, 0, stream>>>(xn2, W1t, b1, nullptr, ffn1, CCH, 4 * CCH);
  // FFN2 (+residual x1) -> d_out fp32
  k_mgemm<false, true, false><<<gM, blk, 0, stream>>>(ffn1, W2t, b2, x1, out, 4 * CCH, CCH);
}